// Round 1
// baseline (330.835 us; speedup 1.0000x reference)
//
#include <hip/hip_runtime.h>

// Sinkhorn on 8192 independent 64x64 matrices.
// Key restructure: linear-space scaling-vector Sinkhorn (u,v form).
//   A0[r][c] = exp2(t - rowmax(t)),  t = (softplus(-gamma)+noise)*10*log2(e)
//   iterate: u = 1/(A0 v) [row sums], v = 1/(A0^T u) [col sums]
//   out = diag(u) A0 diag(v)   (ref ends on col-norm, so out = exp(log_alpha))
// One wave per matrix; lane (lr,lc) owns the 8x8 tile rows lr*8..+7, cols lc*8..+7.
// Row reduce: in-lane 8 + DPP butterfly xor1(quad_perm)/xor2(quad_perm)/xor7(row_half_mirror).
// Col reduce: in-lane 8 + xor8(row_ror:8 DPP) + xor16(ds_swizzle) + xor32(ds_bpermute).

#define L2E   1.4426950408889634f
#define SCALE 14.426950408889634f   // 10 * log2(e)  (temp 0.1, base-2 domain)
#define NITER 50

template<int CTRL>
__device__ __forceinline__ float dppmov(float x) {
  return __int_as_float(__builtin_amdgcn_update_dpp(
      0, __float_as_int(x), CTRL, 0xF, 0xF, true));
}
// xor1 within quads: quad_perm [1,0,3,2] = 0xB1
// xor2 within quads: quad_perm [2,3,0,1] = 0x4E
// xor7 within 8:     row_half_mirror     = 0x141
// xor8 within 16:    row_ror:8           = 0x128

__device__ __forceinline__ float swz_x16(float x) {  // lane ^= 16 (within 32)
  return __int_as_float(__builtin_amdgcn_ds_swizzle(__float_as_int(x), 0x401F));
}
__device__ __forceinline__ float bperm(int addr, float x) {  // arbitrary 64-lane pull
  return __int_as_float(__builtin_amdgcn_ds_bpermute(addr, __float_as_int(x)));
}

__global__ __launch_bounds__(256) void sinkhorn64(
    const float* __restrict__ gamma,
    const float* __restrict__ noise,
    float* __restrict__ out, int batch) {
  const int lane = threadIdx.x & 63;
  const int m = blockIdx.x * 4 + (threadIdx.x >> 6);
  if (m >= batch) return;

  const int lr = lane >> 3;        // row group (bits 3..5 of lane)
  const int lc = lane & 7;         // col group (bits 0..2 of lane)
  const int tile_off = (lr * 8) * 64 + lc * 8;
  const float* src  = noise + (size_t)m * 4096 + tile_off;
  const float* gsrc = gamma + tile_off;
  const int addr32 = (lane ^ 32) << 2;   // byte addr for ds_bpermute (lane^32)

  float a[8][8];

  // ---- init: t = softplus(-g)*10*L2E + noise*SCALE ----
#pragma unroll
  for (int i = 0; i < 8; ++i) {
    const float4 n0 = *(const float4*)(src + i * 64);
    const float4 n1 = *(const float4*)(src + i * 64 + 4);
    const float4 g0 = *(const float4*)(gsrc + i * 64);
    const float4 g1 = *(const float4*)(gsrc + i * 64 + 4);
    const float nv[8] = {n0.x, n0.y, n0.z, n0.w, n1.x, n1.y, n1.z, n1.w};
    const float gv[8] = {g0.x, g0.y, g0.z, g0.w, g1.x, g1.y, g1.z, g1.w};
#pragma unroll
    for (int j = 0; j < 8; ++j) {
      // 10*log2(1 + e^{-g}) = 10*log2(1 + 2^{-g*L2E})
      float gp = 10.0f * __builtin_amdgcn_logf(1.0f + __builtin_amdgcn_exp2f(-gv[j] * L2E));
      a[i][j] = fmaf(nv[j], SCALE, gp);
    }
  }

  // ---- rowmax subtraction + exp2 -> A0 (per-row max entry becomes 1.0) ----
#pragma unroll
  for (int i = 0; i < 8; ++i) {
    float mx = fmaxf(fmaxf(fmaxf(a[i][0], a[i][1]), fmaxf(a[i][2], a[i][3])),
                     fmaxf(fmaxf(a[i][4], a[i][5]), fmaxf(a[i][6], a[i][7])));
    mx = fmaxf(mx, dppmov<0xB1>(mx));    // xor1
    mx = fmaxf(mx, dppmov<0x4E>(mx));    // xor2
    mx = fmaxf(mx, dppmov<0x141>(mx));   // xor7  -> full max over the 8 lc-lanes
#pragma unroll
    for (int j = 0; j < 8; ++j)
      a[i][j] = __builtin_amdgcn_exp2f(a[i][j] - mx);
  }

  // ---- scaling-vector Sinkhorn ----
  float u[8], v[8];
#pragma unroll
  for (int j = 0; j < 8; ++j) v[j] = 1.0f;

#pragma unroll 1
  for (int it = 0; it < NITER; ++it) {
    // row phase: u[i] = 1 / sum_c A0[i][c]*v[c]
#pragma unroll
    for (int i = 0; i < 8; ++i) {
      float s = a[i][0] * v[0];
#pragma unroll
      for (int j = 1; j < 8; ++j) s = fmaf(a[i][j], v[j], s);
      s += dppmov<0xB1>(s);
      s += dppmov<0x4E>(s);
      s += dppmov<0x141>(s);
      u[i] = __builtin_amdgcn_rcpf(s);
    }
    // col phase: v[j] = 1 / sum_r A0[r][j]*u[r]
#pragma unroll
    for (int j = 0; j < 8; ++j) {
      float s = a[0][j] * u[0];
#pragma unroll
      for (int i = 1; i < 8; ++i) s = fmaf(a[i][j], u[i], s);
      s += dppmov<0x128>(s);           // xor8
      s += swz_x16(s);                 // xor16
      s += bperm(addr32, s);           // xor32
      v[j] = __builtin_amdgcn_rcpf(s);
    }
  }

  // ---- epilogue: out = diag(u) A0 diag(v) ----
  float* dst = out + (size_t)m * 4096 + tile_off;
#pragma unroll
  for (int i = 0; i < 8; ++i) {
    const float ui = u[i];
    float o[8];
#pragma unroll
    for (int j = 0; j < 8; ++j) o[j] = a[i][j] * ui * v[j];
    *(float4*)(dst + i * 64)     = make_float4(o[0], o[1], o[2], o[3]);
    *(float4*)(dst + i * 64 + 4) = make_float4(o[4], o[5], o[6], o[7]);
  }
}

extern "C" void kernel_launch(void* const* d_in, const int* in_sizes, int n_in,
                              void* d_out, int out_size, void* d_ws, size_t ws_size,
                              hipStream_t stream) {
  const float* gamma = (const float*)d_in[0];
  const float* noise = (const float*)d_in[1];
  float* out = (float*)d_out;
  const int batch = in_sizes[1] / 4096;      // 8192
  const int blocks = (batch + 3) / 4;        // 4 waves (matrices) per block
  sinkhorn64<<<blocks, 256, 0, stream>>>(gamma, noise, out, batch);
}

// Round 4
// 313.467 us; speedup vs baseline: 1.0554x; 1.0554x over previous
//
#include <hip/hip_runtime.h>

// Sinkhorn on 8192 independent 64x64 matrices — scaling-vector (u,v) form.
//   A0 = exp2(t - rowmax(t)),  t = gp + noise*10*log2e,  gp = 10*log2(1+2^(-g*log2e))
//   iterate: u = 1/(A0 v), v = 1/(A0^T u);  out = diag(u) A0 diag(v)
// One wave per matrix; lane (lr,lc) owns the 8x8 tile rows lr*8.., cols lc*8.. .
// A held as v2f pairs -> v_pk_fma_f32.
// Cross-lane via __builtin_amdgcn_update_dpp (compiler handles DPP hazards and
// GCNDPPCombine fuses mov_dpp+add -> v_add_f32_dpp). Raw asm DPP raced (R2 lesson).

typedef float v2f __attribute__((ext_vector_type(2)));

#define L2E   1.4426950408889634f
#define SCALE 14.426950408889634f   // 10 * log2(e)
#define NITER 50

template<int CTRL>
__device__ __forceinline__ float dppmov(float x) {
  return __int_as_float(__builtin_amdgcn_update_dpp(
      0, __float_as_int(x), CTRL, 0xF, 0xF, true));
}
// xor1: quad_perm [1,0,3,2] = 0xB1 ; xor2: quad_perm [2,3,0,1] = 0x4E
// xor7: row_half_mirror = 0x141    ; xor8: row_ror:8 = 0x128

__device__ __forceinline__ float swz_x16(float x) {  // value from lane^16 (within 32)
  return __int_as_float(__builtin_amdgcn_ds_swizzle(__float_as_int(x), 0x401F));
}
__device__ __forceinline__ float bperm(int addr, float x) {
  return __int_as_float(__builtin_amdgcn_ds_bpermute(addr, __float_as_int(x)));
}

// gp = 10*log2(1 + 2^(-g*log2e))  (== softplus(-g)/temp in base-2 domain), 4096 elems
__global__ __launch_bounds__(256) void prep_gp(const float* __restrict__ g,
                                               float* __restrict__ gp) {
  const int i = blockIdx.x * 256 + threadIdx.x;
  const float x = g[i];
  gp[i] = 10.0f * __builtin_amdgcn_logf(1.0f + __builtin_amdgcn_exp2f(-x * L2E));
}

__global__ __launch_bounds__(256, 3) void sinkhorn64(
    const float* __restrict__ gp,      // may be null -> compute from gamma
    const float* __restrict__ gamma,
    const float* __restrict__ noise,
    float* __restrict__ out, int batch) {
  const int lane = threadIdx.x & 63;
  const int m = blockIdx.x * 4 + (threadIdx.x >> 6);
  if (m >= batch) return;

  const int lr = lane >> 3;
  const int lc = lane & 7;
  const int tile_off = (lr * 8) * 64 + lc * 8;
  const float* src = noise + (size_t)m * 4096 + tile_off;
  const int addr32 = (lane ^ 32) << 2;

  v2f a2[8][4];   // a2[i][jj] = (A[row i][col 2jj], A[row i][col 2jj+1]) of 8x8 tile

  // ---- init: t = gp + noise*SCALE ----
#pragma unroll
  for (int i = 0; i < 8; ++i) {
    const float4 n0 = *(const float4*)(src + i * 64);
    const float4 n1 = *(const float4*)(src + i * 64 + 4);
    const v2f n2[4] = {{n0.x, n0.y}, {n0.z, n0.w}, {n1.x, n1.y}, {n1.z, n1.w}};
    v2f g2[4];
    if (gp) {
      const float4 g0 = *(const float4*)(gp + tile_off + i * 64);
      const float4 g1 = *(const float4*)(gp + tile_off + i * 64 + 4);
      g2[0] = (v2f){g0.x, g0.y}; g2[1] = (v2f){g0.z, g0.w};
      g2[2] = (v2f){g1.x, g1.y}; g2[3] = (v2f){g1.z, g1.w};
    } else {
      const float4 g0 = *(const float4*)(gamma + tile_off + i * 64);
      const float4 g1 = *(const float4*)(gamma + tile_off + i * 64 + 4);
      const float gv[8] = {g0.x, g0.y, g0.z, g0.w, g1.x, g1.y, g1.z, g1.w};
      float gq[8];
#pragma unroll
      for (int j = 0; j < 8; ++j)
        gq[j] = 10.0f * __builtin_amdgcn_logf(1.0f + __builtin_amdgcn_exp2f(-gv[j] * L2E));
      g2[0] = (v2f){gq[0], gq[1]}; g2[1] = (v2f){gq[2], gq[3]};
      g2[2] = (v2f){gq[4], gq[5]}; g2[3] = (v2f){gq[6], gq[7]};
    }
    const v2f sc2 = {SCALE, SCALE};
#pragma unroll
    for (int jj = 0; jj < 4; ++jj)
      a2[i][jj] = __builtin_elementwise_fma(n2[jj], sc2, g2[jj]);
  }

  // ---- rowmax subtraction + exp2 ----
#pragma unroll
  for (int i = 0; i < 8; ++i) {
    v2f m2 = __builtin_elementwise_max(
        __builtin_elementwise_max(a2[i][0], a2[i][1]),
        __builtin_elementwise_max(a2[i][2], a2[i][3]));
    float mx = fmaxf(m2.x, m2.y);
    mx = fmaxf(mx, dppmov<0xB1>(mx));
    mx = fmaxf(mx, dppmov<0x4E>(mx));
    mx = fmaxf(mx, dppmov<0x141>(mx));
    const v2f mx2 = {mx, mx};
#pragma unroll
    for (int jj = 0; jj < 4; ++jj) {
      const v2f d = a2[i][jj] - mx2;
      a2[i][jj] = (v2f){__builtin_amdgcn_exp2f(d.x), __builtin_amdgcn_exp2f(d.y)};
    }
  }

  // ---- scaling-vector Sinkhorn ----
  v2f vv[4];
#pragma unroll
  for (int jj = 0; jj < 4; ++jj) vv[jj] = (v2f){1.0f, 1.0f};
  float u[8];

#pragma unroll 1
  for (int it = 0; it < NITER; ++it) {
    // row phase: u[i] = 1/sum_c A[i][c] v[c]
#pragma unroll
    for (int i = 0; i < 8; ++i) {
      v2f s2 = a2[i][0] * vv[0];
      s2 = __builtin_elementwise_fma(a2[i][1], vv[1], s2);
      s2 = __builtin_elementwise_fma(a2[i][2], vv[2], s2);
      s2 = __builtin_elementwise_fma(a2[i][3], vv[3], s2);
      float s = s2.x + s2.y;
      s += dppmov<0xB1>(s);
      s += dppmov<0x4E>(s);
      s += dppmov<0x141>(s);
      u[i] = __builtin_amdgcn_rcpf(s);
    }
    // col phase: v[j] = 1/sum_r A[r][j] u[r]
    v2f ub[8];
#pragma unroll
    for (int i = 0; i < 8; ++i) ub[i] = (v2f){u[i], u[i]};
#pragma unroll
    for (int jj = 0; jj < 4; ++jj) {
      v2f s2 = a2[0][jj] * ub[0];
#pragma unroll
      for (int i = 1; i < 8; ++i) s2 = __builtin_elementwise_fma(a2[i][jj], ub[i], s2);
      float sx = s2.x, sy = s2.y;
      sx += dppmov<0x128>(sx);
      sx += swz_x16(sx);
      sx += bperm(addr32, sx);
      sy += dppmov<0x128>(sy);
      sy += swz_x16(sy);
      sy += bperm(addr32, sy);
      vv[jj] = (v2f){__builtin_amdgcn_rcpf(sx), __builtin_amdgcn_rcpf(sy)};
    }
  }

  // ---- epilogue: out = diag(u) A0 diag(v) ----
  float* dst = out + (size_t)m * 4096 + tile_off;
#pragma unroll
  for (int i = 0; i < 8; ++i) {
    const v2f ui2 = (v2f){u[i], u[i]};
    v2f o2[4];
#pragma unroll
    for (int jj = 0; jj < 4; ++jj) o2[jj] = a2[i][jj] * ui2 * vv[jj];
    *(float4*)(dst + i * 64)     = make_float4(o2[0].x, o2[0].y, o2[1].x, o2[1].y);
    *(float4*)(dst + i * 64 + 4) = make_float4(o2[2].x, o2[2].y, o2[3].x, o2[3].y);
  }
}

extern "C" void kernel_launch(void* const* d_in, const int* in_sizes, int n_in,
                              void* d_out, int out_size, void* d_ws, size_t ws_size,
                              hipStream_t stream) {
  const float* gamma = (const float*)d_in[0];
  const float* noise = (const float*)d_in[1];
  float* out = (float*)d_out;
  const int batch = in_sizes[1] / 4096;      // 8192
  const int blocks = (batch + 3) / 4;

  float* gp = nullptr;
  if (ws_size >= 4096 * sizeof(float)) {
    gp = (float*)d_ws;
    prep_gp<<<16, 256, 0, stream>>>(gamma, gp);
  }
  sinkhorn64<<<blocks, 256, 0, stream>>>(gp, gamma, noise, out, batch);
}